// Round 2
// baseline (462.974 us; speedup 1.0000x reference)
//
#include <hip/hip_runtime.h>

#define NUM_CLASSES 601
#define OUT_DIM 27
#define P_ELEMS (NUM_CLASSES * OUT_DIM)   // 16227 floats = 64908 B LDS (< 64 KiB static limit)

typedef float vfloat4 __attribute__((ext_vector_type(4)));

// block=1024 (16 waves), 2 blocks/CU by LDS -> 32 waves/CU (max occupancy).
// __launch_bounds__(1024, 8): 8 waves/EU contract pins VGPR <= 64 so the
// second block stays resident; inner loop needs ~30 VGPRs, no spill expected.
__global__ __launch_bounds__(1024, 8)
void trigram_probs_kernel(const int* __restrict__ idx,
                          const float* __restrict__ W,
                          float4* __restrict__ out4,
                          unsigned n4) {
    __shared__ float P[P_ELEMS];
    const unsigned t = threadIdx.x;

    // ---- Preamble: softmax(W) -> LDS. Single pass of exp (store raw exp,
    // accumulate sum, then normalize in place). 1024 threads cover 601 rows.
    for (unsigned row = t; row < NUM_CLASSES; row += 1024u) {
        const float* w = W + row * OUT_DIM;
        float* p = P + row * OUT_DIM;
        float s = 0.f;
        #pragma unroll
        for (int j = 0; j < OUT_DIM; ++j) { const float v = __expf(w[j]); p[j] = v; s += v; }
        const float inv = 1.0f / s;
        #pragma unroll
        for (int j = 0; j < OUT_DIM; ++j) p[j] *= inv;
    }
    __syncthreads();

    // ---- Main loop: flat float4 gather-store, manually unrolled x2 with
    // independent chains (all idx loads issued before any LDS read) so two
    // memory-latency chains are in flight per wave.
    unsigned i = blockIdx.x * blockDim.x + t;
    const unsigned stride = gridDim.x * blockDim.x;

    for (; i + stride < n4; i += 2u * stride) {
        const unsigned iB = i + stride;
        const unsigned eA = i  * 4u;
        const unsigned eB = iB * 4u;
        const unsigned rA0 = eA / 27u;                 // magic-multiply
        const unsigned rB0 = eB / 27u;
        const unsigned cA0 = eA - rA0 * 27u;
        const unsigned cB0 = eB - rB0 * 27u;
        const unsigned rA1 = rA0 + (cA0 >= 24u);       // float4 spans row r0+1 iff c0 >= 24
        const unsigned rB1 = rB0 + (cB0 >= 24u);

        // Issue all 4 idx loads up front (independent; mostly L1-hit).
        const unsigned baseA0 = (unsigned)idx[rA0] * 27u;
        const unsigned baseA1 = (unsigned)idx[rA1] * 27u;
        const unsigned baseB0 = (unsigned)idx[rB0] * 27u;
        const unsigned baseB1 = (unsigned)idx[rB1] * 27u;

        vfloat4 vA, vB;
        #pragma unroll
        for (int k = 0; k < 4; ++k) {
            const unsigned cA = cA0 + (unsigned)k;
            const unsigned cB = cB0 + (unsigned)k;
            vA[k] = P[(cA < 27u) ? (baseA0 + cA) : (baseA1 + cA - 27u)];
            vB[k] = P[(cB < 27u) ? (baseB0 + cB) : (baseB1 + cB - 27u)];
        }

        // Streaming writes, never re-read: non-temporal to spare L2.
        __builtin_nontemporal_store(vA, (vfloat4*)(out4 + i));
        __builtin_nontemporal_store(vB, (vfloat4*)(out4 + iB));
    }

    // Tail (runs 0 iterations at the exact 4194304x27 shape; kept for safety).
    for (; i < n4; i += stride) {
        const unsigned e  = i * 4u;
        const unsigned r0 = e / 27u;
        const unsigned c0 = e - r0 * 27u;
        const unsigned r1 = r0 + (c0 >= 24u);
        const unsigned base0 = (unsigned)idx[r0] * 27u;
        const unsigned base1 = (unsigned)idx[r1] * 27u;
        vfloat4 v;
        #pragma unroll
        for (int k = 0; k < 4; ++k) {
            const unsigned c = c0 + (unsigned)k;
            v[k] = P[(c < 27u) ? (base0 + c) : (base1 + c - 27u)];
        }
        __builtin_nontemporal_store(v, (vfloat4*)(out4 + i));
    }
}

extern "C" void kernel_launch(void* const* d_in, const int* in_sizes, int n_in,
                              void* d_out, int out_size, void* d_ws, size_t ws_size,
                              hipStream_t stream) {
    const int*   idx = (const int*)d_in[0];   // bigram_idx [4194304] int32
    const float* W   = (const float*)d_in[1]; // W [601,27] float32
    float4*      out = (float4*)d_out;        // probs [4194304,27] float32

    const unsigned n4 = (unsigned)(out_size / 4);  // number of float4 stores
    trigram_probs_kernel<<<dim3(512), dim3(1024), 0, stream>>>(idx, W, out, n4);
}